// Round 1
// baseline (282.018 us; speedup 1.0000x reference)
//
#include <hip/hip_runtime.h>

#define BLOCK 256
#define GRID  2048

__device__ __forceinline__ float kl_elem(float p, float q) {
    // p*(log p - log q) + (1-p)*(log(1-p) - log(1-q))
    float lp  = __logf(p);
    float lq  = __logf(q);
    float l1p = __logf(1.0f - p);
    float l1q = __logf(1.0f - q);
    return p * (lp - lq) + (1.0f - p) * (l1p - l1q);
}

__global__ __launch_bounds__(BLOCK) void kl_div_kernel(
        const float* __restrict__ p,
        const float* __restrict__ q,
        float* __restrict__ out,
        int n) {
    const int nvec = n >> 2;                      // float4 count
    const float4* __restrict__ p4 = reinterpret_cast<const float4*>(p);
    const float4* __restrict__ q4 = reinterpret_cast<const float4*>(q);

    float acc = 0.0f;
    const int stride = gridDim.x * blockDim.x;
    for (int i = blockIdx.x * blockDim.x + threadIdx.x; i < nvec; i += stride) {
        float4 pv = p4[i];
        float4 qv = q4[i];
        acc += kl_elem(pv.x, qv.x);
        acc += kl_elem(pv.y, qv.y);
        acc += kl_elem(pv.z, qv.z);
        acc += kl_elem(pv.w, qv.w);
    }
    // scalar tail (empty for n % 4 == 0, kept for generality)
    for (int i = (nvec << 2) + blockIdx.x * blockDim.x + threadIdx.x; i < n; i += stride) {
        acc += kl_elem(p[i], q[i]);
    }

    // wave-64 shuffle reduction
    #pragma unroll
    for (int off = 32; off > 0; off >>= 1)
        acc += __shfl_down(acc, off, 64);

    __shared__ float wave_sums[BLOCK / 64];
    const int lane = threadIdx.x & 63;
    const int wave = threadIdx.x >> 6;
    if (lane == 0) wave_sums[wave] = acc;
    __syncthreads();

    if (threadIdx.x == 0) {
        float s = 0.0f;
        #pragma unroll
        for (int w = 0; w < BLOCK / 64; ++w) s += wave_sums[w];
        atomicAdd(out, s);   // device-scope by default on CDNA
    }
}

extern "C" void kernel_launch(void* const* d_in, const int* in_sizes, int n_in,
                              void* d_out, int out_size, void* d_ws, size_t ws_size,
                              hipStream_t stream) {
    const float* p = (const float*)d_in[0];
    const float* q = (const float*)d_in[1];
    float* out = (float*)d_out;
    const int n = in_sizes[0];

    // d_out is re-poisoned to 0xAA before every timed launch — zero it.
    hipMemsetAsync(out, 0, sizeof(float), stream);

    kl_div_kernel<<<GRID, BLOCK, 0, stream>>>(p, q, out, n);
}

// Round 2
// 272.654 us; speedup vs baseline: 1.0343x; 1.0343x over previous
//
#include <hip/hip_runtime.h>

#define BLOCK 256
#define GRID  2048
#define VPT   16   // float4 vectors per thread (fast path)
#define BATCH 4    // float4-pairs in flight per batch

__device__ __forceinline__ void kl_acc(float p, float q, float& acc) {
    // log2-space accumulation: acc += p*(log2 p - log2 q) + (1-p)*(log2(1-p) - log2(1-q))
    // (single *ln2 applied once at the end — saves 4 v_mul per element)
    float omp = 1.0f - p;
    float omq = 1.0f - q;
    float d1  = __log2f(p)   - __log2f(q);
    float d2  = __log2f(omp) - __log2f(omq);
    acc = fmaf(p,   d1, acc);
    acc = fmaf(omp, d2, acc);
}

__device__ __forceinline__ void block_reduce_and_atomic(float acc, float* out) {
    const float LN2 = 0.69314718055994530942f;
    #pragma unroll
    for (int off = 32; off > 0; off >>= 1)
        acc += __shfl_down(acc, off, 64);

    __shared__ float wave_sums[BLOCK / 64];
    const int lane = threadIdx.x & 63;
    const int wave = threadIdx.x >> 6;
    if (lane == 0) wave_sums[wave] = acc;
    __syncthreads();

    if (threadIdx.x == 0) {
        float s = 0.0f;
        #pragma unroll
        for (int w = 0; w < BLOCK / 64; ++w) s += wave_sums[w];
        atomicAdd(out, s * LN2);
    }
}

// Fast path: N == GRID*BLOCK*VPT*4, compile-time trip counts, batched loads.
__global__ __launch_bounds__(BLOCK, 8) void kl_div_fast(
        const float4* __restrict__ p4,
        const float4* __restrict__ q4,
        float* __restrict__ out) {
    const int gid = blockIdx.x * BLOCK + threadIdx.x;
    const int stride = GRID * BLOCK;

    float acc0 = 0.0f, acc1 = 0.0f, acc2 = 0.0f, acc3 = 0.0f;

    #pragma unroll
    for (int b = 0; b < VPT / BATCH; ++b) {
        float4 pv[BATCH], qv[BATCH];
        #pragma unroll
        for (int k = 0; k < BATCH; ++k) {
            const int i = gid + (b * BATCH + k) * stride;
            pv[k] = p4[i];
            qv[k] = q4[i];
        }
        #pragma unroll
        for (int k = 0; k < BATCH; ++k) {
            kl_acc(pv[k].x, qv[k].x, acc0);
            kl_acc(pv[k].y, qv[k].y, acc1);
            kl_acc(pv[k].z, qv[k].z, acc2);
            kl_acc(pv[k].w, qv[k].w, acc3);
        }
    }

    float acc = (acc0 + acc1) + (acc2 + acc3);
    block_reduce_and_atomic(acc, out);
}

// Generic fallback: grid-stride, any N.
__global__ __launch_bounds__(BLOCK) void kl_div_generic(
        const float* __restrict__ p,
        const float* __restrict__ q,
        float* __restrict__ out,
        int n) {
    const int nvec = n >> 2;
    const float4* __restrict__ p4 = reinterpret_cast<const float4*>(p);
    const float4* __restrict__ q4 = reinterpret_cast<const float4*>(q);

    float acc = 0.0f;
    const int stride = gridDim.x * blockDim.x;
    for (int i = blockIdx.x * blockDim.x + threadIdx.x; i < nvec; i += stride) {
        float4 pv = p4[i];
        float4 qv = q4[i];
        kl_acc(pv.x, qv.x, acc);
        kl_acc(pv.y, qv.y, acc);
        kl_acc(pv.z, qv.z, acc);
        kl_acc(pv.w, qv.w, acc);
    }
    for (int i = (nvec << 2) + blockIdx.x * blockDim.x + threadIdx.x; i < n; i += stride) {
        kl_acc(p[i], q[i], acc);
    }
    block_reduce_and_atomic(acc, out);
}

extern "C" void kernel_launch(void* const* d_in, const int* in_sizes, int n_in,
                              void* d_out, int out_size, void* d_ws, size_t ws_size,
                              hipStream_t stream) {
    const float* p = (const float*)d_in[0];
    const float* q = (const float*)d_in[1];
    float* out = (float*)d_out;
    const int n = in_sizes[0];

    // d_out is re-poisoned to 0xAA before every timed launch — zero it.
    hipMemsetAsync(out, 0, sizeof(float), stream);

    if (n == GRID * BLOCK * VPT * 4) {
        kl_div_fast<<<GRID, BLOCK, 0, stream>>>(
            reinterpret_cast<const float4*>(p),
            reinterpret_cast<const float4*>(q), out);
    } else {
        kl_div_generic<<<GRID, BLOCK, 0, stream>>>(p, q, out, n);
    }
}